// Round 1
// baseline (645.087 us; speedup 1.0000x reference)
//
#include <hip/hip_runtime.h>

// Problem constants (fixed by setup_inputs)
#define B_SZ   8192
#define CH     5120      // C*H = 20*256
#define K_LAB  10
#define EPS    1e-8f

// Tiling: 16 column-chunks x 32 b-blocks = 512 blocks (2 per CU exactly)
#define COLS   320       // columns per chunk (16*320 = 5120)
#define NCHUNK 16
#define NBB    32        // b-blocks
#define NB     256       // samples per b-block (8192/32)
#define NTHR   320       // 1 thread per column, 5 waves

// One pass over z: per-label column sums S[10][5120] and per-label SSQ[10].
// loss = sum_k (SSQ_k - ||S_k||^2/n_k + n_k*CH*eps^2) / (n_k*CH)
__global__ __launch_bounds__(NTHR) void codi_accum(
    const float* __restrict__ z, const int* __restrict__ labels,
    float* __restrict__ S, float* __restrict__ SSQ)
{
    // (sum, sumsq) per label per column; lab is wave-uniform per sample row,
    // tid stride-1 -> b64 RMW is bank-conflict-free.
    __shared__ float2 acc[K_LAB][COLS];   // 10*320*8 = 25.6 KB
    __shared__ int lab_s[NB];             // block's labels, staged once

    const int tid   = threadIdx.x;                 // 0..319
    const int chunk = blockIdx.x & (NCHUNK - 1);   // 0..15
    const int bblk  = blockIdx.x >> 4;             // 0..31
    const int col   = chunk * COLS + tid;          // 0..5119
    const int b0    = bblk * NB;

    #pragma unroll
    for (int k = 0; k < K_LAB; ++k) acc[k][tid] = make_float2(0.f, 0.f);
    if (tid < NB) lab_s[tid] = labels[b0 + tid];
    __syncthreads();

    const float* zp = z + (size_t)b0 * CH + col;
    #pragma unroll 4
    for (int i = 0; i < NB; ++i) {
        float v = zp[(size_t)i * CH];              // coalesced: lane i -> col i
        // jnp.nan_to_num: NaN->0, +/-inf -> +/-FLT_MAX
        v = (v == v) ? v : 0.0f;
        v = fminf(fmaxf(v, -3.402823466e38f), 3.402823466e38f);
        const int lab = lab_s[i];                  // LDS broadcast read
        float2 a = acc[lab][tid];
        a.x += v;
        a.y = fmaf(v, v, a.y);
        acc[lab][tid] = a;
    }
    __syncthreads();

    // Flush: per-label column sums -> global atomics (disjoint cols per chunk),
    // sumsq wave-reduced then one atomic per wave per label.
    #pragma unroll
    for (int k = 0; k < K_LAB; ++k) {
        float2 a = acc[k][tid];
        atomicAdd(&S[k * CH + col], a.x);
        float q = a.y;
        #pragma unroll
        for (int off = 32; off > 0; off >>= 1) q += __shfl_down(q, off, 64);
        if ((tid & 63) == 0) atomicAdd(&SSQ[k], q);
    }
}

__global__ __launch_bounds__(256) void codi_finalize(
    const float* __restrict__ S, const float* __restrict__ SSQ,
    const int* __restrict__ labels, float* __restrict__ out)
{
    __shared__ int   cnt[K_LAB];
    __shared__ float nsq[K_LAB];
    __shared__ float wsum[4];
    const int tid = threadIdx.x;

    if (tid < K_LAB) cnt[tid] = 0;
    __syncthreads();
    for (int b = tid; b < B_SZ; b += 256) atomicAdd(&cnt[labels[b]], 1);
    __syncthreads();

    for (int k = 0; k < K_LAB; ++k) {
        float local = 0.f;
        for (int j = tid; j < CH; j += 256) {
            float v = S[k * CH + j];
            local = fmaf(v, v, local);
        }
        #pragma unroll
        for (int off = 32; off > 0; off >>= 1) local += __shfl_down(local, off, 64);
        if ((tid & 63) == 0) wsum[tid >> 6] = local;
        __syncthreads();
        if (tid == 0) nsq[k] = wsum[0] + wsum[1] + wsum[2] + wsum[3];
        __syncthreads();
    }

    if (tid == 0) {
        float loss = 0.f;
        for (int k = 0; k < K_LAB; ++k) {
            float n = (float)cnt[k];
            if (n > 0.f) {
                float sse = SSQ[k] - nsq[k] / n + n * (float)CH * (EPS * EPS);
                float mse = sse / (n * (float)CH);
                if (mse == mse) loss += mse;   // nan_to_num(mse_k)
            }
        }
        out[0] = loss;
    }
}

extern "C" void kernel_launch(void* const* d_in, const int* in_sizes, int n_in,
                              void* d_out, int out_size, void* d_ws, size_t ws_size,
                              hipStream_t stream) {
    const float* z      = (const float*)d_in[0];
    const int*   labels = (const int*)d_in[1];

    float* S   = (float*)d_ws;        // K_LAB*CH floats
    float* SSQ = S + K_LAB * CH;      // K_LAB floats

    // ws is re-poisoned to 0xAA before every launch -> zero our accumulators.
    hipMemsetAsync(d_ws, 0, (size_t)(K_LAB * CH + K_LAB) * sizeof(float), stream);

    codi_accum<<<NCHUNK * NBB, NTHR, 0, stream>>>(z, labels, S, SSQ);
    codi_finalize<<<1, 256, 0, stream>>>(S, SSQ, labels, (float*)d_out);
}

// Round 2
// 567.811 us; speedup vs baseline: 1.1361x; 1.1361x over previous
//
#include <hip/hip_runtime.h>

// Problem constants (fixed by setup_inputs)
#define B_SZ   8192
#define CH     5120         // C*H = 20*256
#define CH4    1280         // CH / 4
#define K_LAB  10
#define EPS    1e-8f
#define FLTMAX 3.402823466e38f

#define NTHR   256          // threads per block (4 waves)
#define NCHUNK 5            // column chunks: 5 * 256 thr * 4 cols = 5120
#define UNROLL 8            // prefetch depth (independent dwordx4 in flight)

// loss = sum_{k: n_k>0} (SSQ_k - ||S_k||^2/n_k + n_k*CH*eps^2) / (n_k*CH)
// (the 2*eps cross term cancels exactly since sum(z - mean) == 0)

// Kernel A: one streaming pass over z. Register accumulators (label is
// wave-uniform per sample -> scalar switch). Each block writes a PRIVATE
// partial slice S_part[p][k][1024 cols] -- no atomics on the hot path.
__global__ __launch_bounds__(NTHR) void codi_partial(
    const float4* __restrict__ z4, const int* __restrict__ labels,
    float* __restrict__ S_part, float* __restrict__ SSQ, int SB)
{
    extern __shared__ int lab_s[];                 // SB labels
    const int tid   = threadIdx.x;
    const int chunk = blockIdx.x % NCHUNK;
    const int p     = blockIdx.x / NCHUNK;         // sample-partition index
    const int col4  = chunk * NTHR + tid;          // float4 column 0..1279
    const int b0    = p * SB;

    for (int i = tid; i < SB; i += NTHR) lab_s[i] = labels[b0 + i];
    __syncthreads();

    float4 sum[K_LAB];
    float  ssq[K_LAB];
    #pragma unroll
    for (int k = 0; k < K_LAB; ++k) { sum[k] = make_float4(0,0,0,0); ssq[k] = 0.f; }

    const float4* zp = z4 + (size_t)b0 * CH4 + col4;

    for (int i0 = 0; i0 < SB; i0 += UNROLL) {
        float4 vb[UNROLL];
        #pragma unroll
        for (int u = 0; u < UNROLL; ++u)
            vb[u] = zp[(size_t)(i0 + u) * CH4];    // 8 independent dwordx4

        #pragma unroll
        for (int u = 0; u < UNROLL; ++u) {
            float4 v = vb[u];
            // jnp.nan_to_num: NaN->0, +/-inf -> +/-FLT_MAX
            v.x = (v.x == v.x) ? fminf(fmaxf(v.x, -FLTMAX), FLTMAX) : 0.f;
            v.y = (v.y == v.y) ? fminf(fmaxf(v.y, -FLTMAX), FLTMAX) : 0.f;
            v.z = (v.z == v.z) ? fminf(fmaxf(v.z, -FLTMAX), FLTMAX) : 0.f;
            v.w = (v.w == v.w) ? fminf(fmaxf(v.w, -FLTMAX), FLTMAX) : 0.f;
            float q = fmaf(v.x, v.x, fmaf(v.y, v.y, fmaf(v.z, v.z, v.w * v.w)));
            // label is identical across the wave -> scalar branch, no divergence
            const int lab = __builtin_amdgcn_readfirstlane(lab_s[i0 + u]);
            #define ACC(K) case K: sum[K].x += v.x; sum[K].y += v.y; \
                                   sum[K].z += v.z; sum[K].w += v.w; \
                                   ssq[K] += q; break;
            switch (lab) { ACC(0) ACC(1) ACC(2) ACC(3) ACC(4)
                           ACC(5) ACC(6) ACC(7) ACC(8) ACC(9) }
            #undef ACC
        }
    }

    // Flush: private partial slice (coalesced float4 stores, no atomics)
    float4* sp = (float4*)S_part + ((size_t)p * K_LAB) * CH4 + col4;
    #pragma unroll
    for (int k = 0; k < K_LAB; ++k) sp[(size_t)k * CH4] = sum[k];

    // SSQ: wave-reduce each label, one atomic per wave per label (tiny count)
    #pragma unroll
    for (int k = 0; k < K_LAB; ++k) {
        float q = ssq[k];
        #pragma unroll
        for (int off = 32; off > 0; off >>= 1) q += __shfl_down(q, off, 64);
        if ((tid & 63) == 0) atomicAdd(&SSQ[k], q);
    }
}

// Kernel B: fold P partials directly into ||S_k||^2 (S never materialized).
__global__ __launch_bounds__(NTHR) void codi_reduce(
    const float* __restrict__ S_part, float* __restrict__ nsq, int P)
{
    const int idx = blockIdx.x * NTHR + threadIdx.x;   // 0..51199
    const int k   = idx / CH;
    const int c   = idx - k * CH;
    float s = 0.f;
    #pragma unroll 8
    for (int p = 0; p < P; ++p)
        s += S_part[((size_t)p * K_LAB + k) * CH + c]; // coalesced per p-slice
    float w = s * s;
    // CH % 64 == 0 -> all 64 lanes share the same k
    #pragma unroll
    for (int off = 32; off > 0; off >>= 1) w += __shfl_down(w, off, 64);
    if ((threadIdx.x & 63) == 0) atomicAdd(&nsq[k], w);
}

__global__ __launch_bounds__(NTHR) void codi_final(
    const float* __restrict__ SSQ, const float* __restrict__ nsq,
    const int* __restrict__ labels, float* __restrict__ out)
{
    __shared__ int cnt[K_LAB];
    const int tid = threadIdx.x;
    if (tid < K_LAB) cnt[tid] = 0;
    __syncthreads();
    for (int b = tid; b < B_SZ; b += NTHR) atomicAdd(&cnt[labels[b]], 1);
    __syncthreads();
    if (tid == 0) {
        float loss = 0.f;
        for (int k = 0; k < K_LAB; ++k) {
            float n = (float)cnt[k];
            if (n > 0.f) {
                float sse = SSQ[k] - nsq[k] / n + n * (float)CH * (EPS * EPS);
                float mse = sse / (n * (float)CH);
                if (mse == mse) loss += mse;       // nan_to_num(mse_k)
            }
        }
        out[0] = loss;
    }
}

extern "C" void kernel_launch(void* const* d_in, const int* in_sizes, int n_in,
                              void* d_out, int out_size, void* d_ws, size_t ws_size,
                              hipStream_t stream) {
    const float4* z4     = (const float4*)d_in[0];
    const int*    labels = (const int*)d_in[1];

    // ws layout: [0..9] SSQ, [16..25] nsq, [64..] S_part[P][10][5120]
    float* hdr    = (float*)d_ws;
    float* SSQ    = hdr;
    float* nsq    = hdr + 16;
    float* S_part = hdr + 64;

    // P = sample partitions; pick the largest that fits in ws (26.2 MB @ P=128)
    int P = 128;
    while (P > 4 && 256 + (size_t)P * K_LAB * CH * sizeof(float) > ws_size) P >>= 1;
    const int SB = B_SZ / P;

    hipMemsetAsync(d_ws, 0, 256, stream);  // zero SSQ/nsq header only
    codi_partial<<<NCHUNK * P, NTHR, SB * sizeof(int), stream>>>(
        z4, labels, S_part, SSQ, SB);
    codi_reduce<<<(K_LAB * CH) / NTHR, NTHR, 0, stream>>>(S_part, nsq, P);
    codi_final<<<1, NTHR, 0, stream>>>(SSQ, nsq, labels, (float*)d_out);
}

// Round 3
// 298.889 us; speedup vs baseline: 2.1583x; 1.8997x over previous
//
#include <hip/hip_runtime.h>

// Problem constants (fixed by setup_inputs)
#define B_SZ   8192
#define CH     5120          // C*H = 20*256
#define CH4    1280          // CH / 4
#define K_LAB  10
#define EPS    1e-8f
#define FLTMAX 3.402823466e38f

#define NTHR   256           // gather block (4 waves)
#define NCHUNK 5             // 5 * 256 thr * 4 cols = 5120 columns
#define PS     16            // sample sub-partitions per label
#define PF     8             // loads in flight per thread

// loss = sum_{k: n_k>0} (SSQ_k - ||S_k||^2/n_k + n_k*CH*eps^2) / (n_k*CH)
// (2*eps cross-term cancels exactly: sum_{b in k}(z_b - mu_k) == 0)

// ---------------------------------------------------------------------------
// Setup: per-label ascending index lists. wave k handles label k (10 waves).
__global__ __launch_bounds__(640) void codi_setup(
    const int* __restrict__ labels, int* __restrict__ idx,
    int* __restrict__ off, float* __restrict__ SSQ, float* __restrict__ nsq)
{
    const int tid  = threadIdx.x;
    const int k    = tid >> 6;          // wave index == label
    const int lane = tid & 63;
    __shared__ int cnts[K_LAB];
    __shared__ int offs[K_LAB + 1];

    // pass 1: count label k
    int cnt = 0;
    for (int b0 = 0; b0 < B_SZ; b0 += 64) {
        int lab = labels[b0 + lane];
        cnt += __popcll(__ballot(lab == k));
    }
    if (lane == 0) cnts[k] = cnt;
    __syncthreads();
    if (tid == 0) {
        int a = 0;
        for (int j = 0; j < K_LAB; ++j) { offs[j] = a; a += cnts[j]; }
        offs[K_LAB] = a;
    }
    __syncthreads();

    // pass 2: scatter (ascending b within each label -> deterministic)
    int base = offs[k];
    const unsigned long long ltmask = (1ULL << lane) - 1ULL;  // lanes < me
    for (int b0 = 0; b0 < B_SZ; b0 += 64) {
        int lab = labels[b0 + lane];
        unsigned long long m = __ballot(lab == k);
        if (lab == k) idx[base + __popcll(m & ltmask)] = b0 + lane;
        base += __popcll(m);
    }
    if (tid < K_LAB + 1) off[tid] = offs[tid];
    if (tid < K_LAB) { SSQ[tid] = 0.f; nsq[tid] = 0.f; }
}

// ---------------------------------------------------------------------------
// Main: block = (label k, column chunk, sample sub-range). No label logic in
// the hot loop; accumulators are 5 VGPRs; 8 dwordx4 kept in flight.
__global__ __launch_bounds__(NTHR) void codi_gather(
    const float4* __restrict__ z4, const int* __restrict__ idx,
    const int* __restrict__ off, float4* __restrict__ S_part,
    float* __restrict__ SSQ)
{
    const int tid   = threadIdx.x;
    const int k     = blockIdx.x / (NCHUNK * PS);
    const int rem   = blockIdx.x % (NCHUNK * PS);
    const int chunk = rem % NCHUNK;
    const int ps    = rem / NCHUNK;

    const int kb  = off[k];
    const int cnt = off[k + 1] - kb;
    const int s0  = kb + (int)(((long long)cnt * ps) / PS);
    const int s1  = kb + (int)(((long long)cnt * (ps + 1)) / PS);
    const int n   = s1 - s0;

    __shared__ int rows[544];            // worst case: all of B in one label
    for (int i = tid; i < n; i += NTHR) rows[i] = idx[s0 + i];
    __syncthreads();

    const int col4 = chunk * NTHR + tid; // float4 column 0..1279
    float4 sum = make_float4(0.f, 0.f, 0.f, 0.f);
    float  ssq = 0.f;

    for (int i0 = 0; i0 < n; i0 += PF) {
        int r[PF];
        #pragma unroll
        for (int u = 0; u < PF; ++u)
            if (i0 + u < n) r[u] = rows[i0 + u];

        float4 vb[PF];
        #pragma unroll
        for (int u = 0; u < PF; ++u)
            if (i0 + u < n) vb[u] = z4[(size_t)r[u] * CH4 + col4];

        #pragma unroll
        for (int u = 0; u < PF; ++u) {
            if (i0 + u < n) {
                float4 v = vb[u];
                // jnp.nan_to_num: NaN->0, +/-inf -> +/-FLT_MAX
                v.x = (v.x == v.x) ? fminf(fmaxf(v.x, -FLTMAX), FLTMAX) : 0.f;
                v.y = (v.y == v.y) ? fminf(fmaxf(v.y, -FLTMAX), FLTMAX) : 0.f;
                v.z = (v.z == v.z) ? fminf(fmaxf(v.z, -FLTMAX), FLTMAX) : 0.f;
                v.w = (v.w == v.w) ? fminf(fmaxf(v.w, -FLTMAX), FLTMAX) : 0.f;
                sum.x += v.x; sum.y += v.y; sum.z += v.z; sum.w += v.w;
                ssq = fmaf(v.x, v.x, ssq); ssq = fmaf(v.y, v.y, ssq);
                ssq = fmaf(v.z, v.z, ssq); ssq = fmaf(v.w, v.w, ssq);
            }
        }
    }

    // private partial slice, written unconditionally (n may be 0)
    S_part[((size_t)(k * PS + ps)) * CH4 + col4] = sum;

    #pragma unroll
    for (int o = 32; o > 0; o >>= 1) ssq += __shfl_down(ssq, o, 64);
    if ((tid & 63) == 0) atomicAdd(&SSQ[k], ssq);
}

// ---------------------------------------------------------------------------
// Fold the PS partials straight into ||S_k||^2.
__global__ __launch_bounds__(NTHR) void codi_reduce(
    const float* __restrict__ S_part, float* __restrict__ nsq)
{
    const int i = blockIdx.x * NTHR + threadIdx.x;   // 0..51199
    const int k = i / CH;
    const int c = i - k * CH;
    float s = 0.f;
    #pragma unroll
    for (int ps = 0; ps < PS; ++ps)
        s += S_part[((size_t)(k * PS + ps)) * CH + c];
    float w = s * s;
    #pragma unroll
    for (int o = 32; o > 0; o >>= 1) w += __shfl_down(w, o, 64);
    if ((threadIdx.x & 63) == 0) atomicAdd(&nsq[k], w);  // CH%64==0 -> k uniform
}

__global__ __launch_bounds__(64) void codi_final(
    const int* __restrict__ off, const float* __restrict__ SSQ,
    const float* __restrict__ nsq, float* __restrict__ out)
{
    if (threadIdx.x == 0) {
        float loss = 0.f;
        for (int k = 0; k < K_LAB; ++k) {
            float n = (float)(off[k + 1] - off[k]);
            if (n > 0.f) {
                float sse = SSQ[k] - nsq[k] / n + n * (float)CH * (EPS * EPS);
                float mse = sse / (n * (float)CH);
                if (mse == mse) loss += mse;     // nan_to_num(mse_k)
            }
        }
        out[0] = loss;
    }
}

// ---------------------------------------------------------------------------
extern "C" void kernel_launch(void* const* d_in, const int* in_sizes, int n_in,
                              void* d_out, int out_size, void* d_ws, size_t ws_size,
                              hipStream_t stream) {
    const float4* z4     = (const float4*)d_in[0];
    const int*    labels = (const int*)d_in[1];

    // ws layout (floats): [0..9] SSQ, [16..25] nsq, [32..47] off[11],
    //                     [64..8255] idx[8192], [8256..] S_part[10][PS][5120]
    float* hdr    = (float*)d_ws;
    float* SSQ    = hdr;
    float* nsq    = hdr + 16;
    int*   off    = (int*)(hdr + 32);
    int*   idx    = (int*)(hdr + 64);
    float* S_part = hdr + 64 + B_SZ;

    codi_setup<<<1, 640, 0, stream>>>(labels, idx, off, SSQ, nsq);
    codi_gather<<<K_LAB * NCHUNK * PS, NTHR, 0, stream>>>(
        z4, idx, off, (float4*)S_part, SSQ);
    codi_reduce<<<(K_LAB * CH) / NTHR, NTHR, 0, stream>>>(S_part, nsq);
    codi_final<<<1, 64, 0, stream>>>(off, SSQ, nsq, (float*)d_out);
}